// Round 1
// baseline (348.526 us; speedup 1.0000x reference)
//
#include <hip/hip_runtime.h>
#include <math.h>

#define BB 2
#define NN 4096
#define KK 2048
#define CC 16
#define DSPAN_ 2048
#define EDIM 300
#define HDIM 512

// ---------------------------------------------------------------------------
// Kernel 1: span_part[r, h] = sum_d cand_span_vecs[b, idx[r], d] * W1[d, h]
// M = B*K = 4096 (gathered rows), N = 512, K = 2048. f32 LDS-tiled GEMM.
// ---------------------------------------------------------------------------
__global__ __launch_bounds__(256) void span_gemm(
    const float* __restrict__ span,   // [B, N, DSPAN]
    const float* __restrict__ W1,     // [DSPAN+E, H]
    const int*   __restrict__ lidx,   // [B, K] flat
    float*       __restrict__ out)    // [B*K, H]
{
    const int BM = 64, BN = 64, BKt = 16;
    __shared__ float As[BKt][BM + 4];   // row stride 68 floats (16B-aligned rows)
    __shared__ float Bs[BKt][BN + 4];

    const int tid = threadIdx.x;
    const int tx = tid & 15;      // 0..15 -> output col group
    const int ty = tid >> 4;      // 0..15 -> output row group
    const int rowBase = blockIdx.y * BM;
    const int colBase = blockIdx.x * BN;

    // A-load mapping: kk = tid&15 (contiguous along K), row = tid>>4, 4 passes
    const int lkk = tid & 15;
    const int lm  = tid >> 4;
    const float* aptr[4];
#pragma unroll
    for (int p = 0; p < 4; ++p) {
        int r   = rowBase + lm + 16 * p;
        int b   = r / KK;
        int idx = lidx[r];
        aptr[p] = span + ((size_t)b * NN + (size_t)idx) * DSPAN_;
    }

    // B-load mapping: n = tid&63 (contiguous cols), k-row = tid>>6, 4 passes
    const int ln  = tid & 63;
    const int lkb = tid >> 6;

    float acc[4][4] = {};

    for (int k0 = 0; k0 < DSPAN_; k0 += BKt) {
#pragma unroll
        for (int p = 0; p < 4; ++p)
            As[lkk][lm + 16 * p] = aptr[p][k0 + lkk];
#pragma unroll
        for (int p = 0; p < 4; ++p)
            Bs[lkb + 4 * p][ln] =
                W1[(size_t)(k0 + lkb + 4 * p) * HDIM + colBase + ln];
        __syncthreads();

#pragma unroll
        for (int kk = 0; kk < BKt; ++kk) {
            float4 av = *(const float4*)&As[kk][ty * 4];
            float4 bv = *(const float4*)&Bs[kk][tx * 4];
            float aa[4] = {av.x, av.y, av.z, av.w};
            float bb[4] = {bv.x, bv.y, bv.z, bv.w};
#pragma unroll
            for (int i = 0; i < 4; ++i)
#pragma unroll
                for (int j = 0; j < 4; ++j)
                    acc[i][j] = fmaf(aa[i], bb[j], acc[i][j]);
        }
        __syncthreads();
    }

#pragma unroll
    for (int i = 0; i < 4; ++i) {
        float4 v = make_float4(acc[i][0], acc[i][1], acc[i][2], acc[i][3]);
        *(float4*)&out[(size_t)(rowBase + ty * 4 + i) * HDIM + colBase + tx * 4] = v;
    }
}

// ---------------------------------------------------------------------------
// Kernel 2: per (b,k) block. Stage <=16 entity rows in LDS, accumulate
// h[c][:] = span_part + b1 + emb[c] @ W1_ent in registers (2 cols/thread),
// then fused ReLU -> dot(W2) -> stable BCE -> per-block partial sum.
// ---------------------------------------------------------------------------
__global__ __launch_bounds__(256) void ent_score(
    const float* __restrict__ span_part, // [B*K, H]
    const float* __restrict__ W1e,       // W1 + DSPAN*H, [E, H]
    const float* __restrict__ b1,        // [H]
    const float* __restrict__ W2,        // [H]
    const float* __restrict__ b2,        // [1]
    const float* __restrict__ emb,       // [V, E]
    const float* __restrict__ targets,   // [B, N, C]
    const int*   __restrict__ lidx,      // [B, K]
    const int*   __restrict__ cands,     // [B, N, C]
    const int*   __restrict__ clens,     // [B, N]
    float*       __restrict__ blockPartial) // [B*K]
{
    __shared__ float ent[CC * EDIM];   // 19200 B
    __shared__ float red[CC][5];
    __shared__ float bceArr[CC];

    const int bk = blockIdx.x;
    const int t  = threadIdx.x;
    const int b  = bk >> 11;          // / 2048
    const int idx = lidx[bk];
    const size_t base = (size_t)b * NN + (size_t)idx;
    int len = clens[base];
    if (len > CC) len = CC;
    if (len < 0)  len = 0;

    // stage entity rows for valid candidates
    for (int c = 0; c < len; ++c) {
        int cd = cands[base * CC + c];
        const float* erow = emb + (size_t)cd * EDIM;
        for (int j = t; j < EDIM; j += 256) ent[c * EDIM + j] = erow[j];
    }

    const float sp0 = span_part[(size_t)bk * HDIM + t]       + b1[t];
    const float sp1 = span_part[(size_t)bk * HDIM + 256 + t] + b1[256 + t];

    float acc0[CC], acc1[CC];
#pragma unroll
    for (int c = 0; c < CC; ++c) { acc0[c] = sp0; acc1[c] = sp1; }

    __syncthreads();

    for (int e0 = 0; e0 < EDIM; e0 += 4) {
        const float* wp = W1e + (size_t)e0 * HDIM + t;
        float w00 = wp[0];
        float w01 = wp[HDIM];
        float w02 = wp[2 * HDIM];
        float w03 = wp[3 * HDIM];
        float w10 = wp[256];
        float w11 = wp[HDIM + 256];
        float w12 = wp[2 * HDIM + 256];
        float w13 = wp[3 * HDIM + 256];
#pragma unroll
        for (int c = 0; c < CC; ++c) {
            if (c < len) {   // uniform (len is block-uniform) -> scalar branch
                float4 ev = *(const float4*)&ent[c * EDIM + e0];
                acc0[c] = fmaf(ev.x, w00, acc0[c]);
                acc0[c] = fmaf(ev.y, w01, acc0[c]);
                acc0[c] = fmaf(ev.z, w02, acc0[c]);
                acc0[c] = fmaf(ev.w, w03, acc0[c]);
                acc1[c] = fmaf(ev.x, w10, acc1[c]);
                acc1[c] = fmaf(ev.y, w11, acc1[c]);
                acc1[c] = fmaf(ev.z, w12, acc1[c]);
                acc1[c] = fmaf(ev.w, w13, acc1[c]);
            }
        }
    }

    // fused epilogue: relu -> dot with W2 -> block reduce -> BCE
    const float w2a = W2[t];
    const float w2b = W2[256 + t];
#pragma unroll
    for (int c = 0; c < CC; ++c) {
        if (c >= len) break;   // uniform
        float v = fmaxf(acc0[c], 0.f) * w2a + fmaxf(acc1[c], 0.f) * w2b;
#pragma unroll
        for (int off = 32; off; off >>= 1) v += __shfl_xor(v, off, 64);
        if ((t & 63) == 0) red[c][t >> 6] = v;
    }
    __syncthreads();

    if (t < len) {
        float score = red[t][0] + red[t][1] + red[t][2] + red[t][3] + b2[0];
        float tgt   = targets[base * CC + t];
        // stable softplus: max(x,0) + log1p(exp(-|x|))
        float sp = fmaxf(score, 0.f) + log1pf(expf(-fabsf(score)));
        bceArr[t] = sp - score * tgt;
    }
    __syncthreads();

    if (t == 0) {
        float s = 0.f;
        for (int c = 0; c < len; ++c) s += bceArr[c];
        blockPartial[bk] = s;
    }
}

// ---------------------------------------------------------------------------
// Kernel 3: deterministic final reduction of 4096 block partials -> d_out[0]
// ---------------------------------------------------------------------------
__global__ __launch_bounds__(256) void reduce_partials(
    const float* __restrict__ p, int n, float* __restrict__ out)
{
    __shared__ float red[4];
    float s = 0.f;
    for (int i = threadIdx.x; i < n; i += 256) s += p[i];
#pragma unroll
    for (int off = 32; off; off >>= 1) s += __shfl_xor(s, off, 64);
    if ((threadIdx.x & 63) == 0) red[threadIdx.x >> 6] = s;
    __syncthreads();
    if (threadIdx.x == 0)
        out[0] = (red[0] + red[1] + red[2] + red[3]) * 1.0f; // WEIGHT = 1.0
}

// ---------------------------------------------------------------------------
extern "C" void kernel_launch(void* const* d_in, const int* in_sizes, int n_in,
                              void* d_out, int out_size, void* d_ws, size_t ws_size,
                              hipStream_t stream) {
    const float* span    = (const float*)d_in[0]; // [B,N,DSPAN]
    const float* targets = (const float*)d_in[1]; // [B,N,C]
    const float* emb     = (const float*)d_in[2]; // [V,E]
    const float* W1      = (const float*)d_in[3]; // [DSPAN+E, H]
    const float* b1      = (const float*)d_in[4]; // [H]
    const float* W2      = (const float*)d_in[5]; // [H,1]
    const float* b2      = (const float*)d_in[6]; // [1]
    const int*   lidx    = (const int*)d_in[7];   // [B,K]
    const int*   cands   = (const int*)d_in[8];   // [B,N,C]
    const int*   clens   = (const int*)d_in[9];   // [B,N]

    float* span_part = (float*)d_ws;                        // B*K*H f32 = 8 MB
    float* partials  = span_part + (size_t)BB * KK * HDIM;  // B*K f32

    dim3 g1(HDIM / 64, (BB * KK) / 64);
    span_gemm<<<g1, 256, 0, stream>>>(span, W1, lidx, span_part);

    ent_score<<<BB * KK, 256, 0, stream>>>(
        span_part, W1 + (size_t)DSPAN_ * HDIM, b1, W2, b2, emb, targets,
        lidx, cands, clens, partials);

    reduce_partials<<<1, 256, 0, stream>>>(partials, BB * KK, (float*)d_out);
}

// Round 2
// 96.604 us; speedup vs baseline: 3.6078x; 3.6078x over previous
//
#include <hip/hip_runtime.h>
#include <math.h>

#define BBATCH 2
#define NN 4096
#define KSEL 2048
#define CC 16
#define DSP 2048
#define ED 300
#define HD 512

typedef __attribute__((ext_vector_type(8))) short short8;
typedef __attribute__((ext_vector_type(4))) float f32x4;

#define MFMA16(a, b, c) __builtin_amdgcn_mfma_f32_16x16x32_bf16((a), (b), (c), 0, 0, 0)

__device__ __forceinline__ unsigned short f2bf(float x) {
    unsigned u = __builtin_bit_cast(unsigned, x);
    u += 0x7FFFu + ((u >> 16) & 1u);   // RNE
    return (unsigned short)(u >> 16);
}

__device__ __forceinline__ void gl_lds16(const void* g, void* l) {
    __builtin_amdgcn_global_load_lds(
        (const __attribute__((address_space(1))) unsigned*)g,
        (__attribute__((address_space(3))) unsigned*)l, 16, 0, 0);
}

// ---------------------------------------------------------------------------
// Weight prep.
// blocks 0..255: W1sT[n][k] = bf16(W1[k][n])  (n<512, k<2048), 64x64 LDS tiles
// blocks 256..335: w1ef fragment-ready entity weights:
//   w1ef[((ncg*10 + ks)*64 + lane)*8 + j] = bf16(W1[2048+k][ncg*16+(lane&15)]),
//   k = ks*32 + (lane>>4)*8 + j, zero for k >= 300.
// ---------------------------------------------------------------------------
__global__ __launch_bounds__(256) void prep_weights(
    const float* __restrict__ W1,
    unsigned short* __restrict__ W1sT,
    unsigned short* __restrict__ w1ef)
{
    __shared__ float t[64][65];
    const int bid = blockIdx.x, tid = threadIdx.x;
    if (bid < 256) {
        const int k0 = (bid >> 3) * 64, n0 = (bid & 7) * 64;
#pragma unroll
        for (int p = 0; p < 16; ++p) {
            int flat = p * 256 + tid;
            int r = flat >> 6, c = flat & 63;
            t[r][c] = W1[(size_t)(k0 + r) * HD + n0 + c];
        }
        __syncthreads();
#pragma unroll
        for (int p = 0; p < 16; ++p) {
            int flat = p * 256 + tid;
            int c = flat >> 6, r = flat & 63;
            W1sT[(size_t)(n0 + c) * DSP + k0 + r] = f2bf(t[r][c]);
        }
    } else {
        int t0 = (bid - 256) * 256 + tid;   // 0..20479
        int lane = t0 & 63;
        int ks = (t0 >> 6) % 10;
        int ncg = (t0 >> 6) / 10;
        int col = ncg * 16 + (lane & 15);
        int kb = ks * 32 + ((lane >> 4) << 3);
        unsigned short v[8];
#pragma unroll
        for (int j = 0; j < 8; ++j) {
            int k = kb + j;
            v[j] = (k < ED) ? f2bf(W1[(size_t)(DSP + k) * HD + col]) : (unsigned short)0;
        }
        *(short8*)&w1ef[(size_t)t0 * 8] = *(short8*)v;
    }
}

// ---------------------------------------------------------------------------
// Gather selected span rows -> bf16 A16[bk][2048]
// ---------------------------------------------------------------------------
__global__ __launch_bounds__(256) void gather_span(
    const float* __restrict__ span, const int* __restrict__ lidx,
    unsigned short* __restrict__ A16)
{
    const int bk = blockIdx.x, tid = threadIdx.x;
    const int b = bk >> 11;
    const int idx = lidx[bk];
    const float* src = span + ((size_t)b * NN + idx) * DSP;
    float4 x = *(const float4*)(src + tid * 8);
    float4 y = *(const float4*)(src + tid * 8 + 4);
    unsigned short v[8] = { f2bf(x.x), f2bf(x.y), f2bf(x.z), f2bf(x.w),
                            f2bf(y.x), f2bf(y.y), f2bf(y.z), f2bf(y.w) };
    *(short8*)&A16[(size_t)bk * DSP + tid * 8] = *(short8*)v;
}

// ---------------------------------------------------------------------------
// Span GEMM (MFMA bf16): C[4096][512] = A16 @ W1s + b1.
// BM=128, BN=64, BK=32; 4 waves 2x2, wave tile 64x32; global_load_lds w=16.
// ---------------------------------------------------------------------------
__global__ __launch_bounds__(256) void span_gemm(
    const unsigned short* __restrict__ A16,   // [4096][2048] bf16
    const unsigned short* __restrict__ BT,    // [512][2048]  bf16 (W1s^T)
    const float* __restrict__ b1,
    float* __restrict__ Cout)                 // [4096][512] f32 (+b1)
{
    __shared__ unsigned short As[128 * 32];
    __shared__ unsigned short Bs[64 * 32];
    const int tid = threadIdx.x;
    const int l = tid & 63, wid = tid >> 6;
    const int wr = (wid >> 1) * 64, wc = (wid & 1) * 32;
    const int brow = blockIdx.y * 128, bcol = blockIdx.x * 64;

    f32x4 z = {0.f, 0.f, 0.f, 0.f};
    f32x4 acc[4][2];
#pragma unroll
    for (int m = 0; m < 4; ++m)
#pragma unroll
        for (int n = 0; n < 2; ++n) acc[m][n] = z;

    for (int k0 = 0; k0 < DSP; k0 += 32) {
        {
            int row = tid >> 2, kq = tid & 3;     // B: 256 slots
            gl_lds16(BT + (size_t)(bcol + row) * DSP + k0 + kq * 8,
                     (unsigned short*)Bs + tid * 8);
#pragma unroll
            for (int p = 0; p < 2; ++p) {         // A: 512 slots
                int sa = p * 256 + tid;
                int ra = sa >> 2, kqa = sa & 3;
                gl_lds16(A16 + (size_t)(brow + ra) * DSP + k0 + kqa * 8,
                         (unsigned short*)As + sa * 8);
            }
        }
        __syncthreads();
        short8 am[4], bn[2];
#pragma unroll
        for (int m = 0; m < 4; ++m)
            am[m] = *(const short8*)&As[(wr + m * 16 + (l & 15)) * 32 + (l >> 4) * 8];
#pragma unroll
        for (int n = 0; n < 2; ++n)
            bn[n] = *(const short8*)&Bs[(wc + n * 16 + (l & 15)) * 32 + (l >> 4) * 8];
#pragma unroll
        for (int m = 0; m < 4; ++m)
#pragma unroll
            for (int n = 0; n < 2; ++n)
                acc[m][n] = MFMA16(am[m], bn[n], acc[m][n]);
        __syncthreads();
    }

#pragma unroll
    for (int n = 0; n < 2; ++n) {
        int col = bcol + wc + n * 16 + (l & 15);
        float b1v = b1[col];
#pragma unroll
        for (int m = 0; m < 4; ++m) {
            int row0 = brow + wr + m * 16 + (l >> 4) * 4;
#pragma unroll
            for (int r = 0; r < 4; ++r)
                Cout[(size_t)(row0 + r) * HD + col] = acc[m][n][r] + b1v;
        }
    }
}

// ---------------------------------------------------------------------------
// Entity MFMA + fused epilogue.
// Block = 512 thr (8 waves), covers 8 bk pairs x all 512 h-cols.
// Wave w owns 64-col slice ht=w. Per K-step (K=32, 10 steps over padded 320):
// all 512 threads stage A-frags (8 bk x 64 lanes x 16B) f32->bf16 into LDS.
// Epilogue: relu(acc + span_h)*W2, shuffle-reduce over cols -> partials.
// ---------------------------------------------------------------------------
__global__ __launch_bounds__(512) void ent_mfma(
    const unsigned short* __restrict__ w1ef,
    const float* __restrict__ span_part,  // [4096][512], includes b1
    const float* __restrict__ emb,        // [V][300] f32
    const float* __restrict__ W2,         // [512]
    const int* __restrict__ lidx,         // [B*K]
    const int* __restrict__ cands,        // [B*N*16]
    float* __restrict__ partials)         // [4096*16*8]
{
    __shared__ unsigned short As[8 * 64 * 8];   // 8 KB
    const int tid = threadIdx.x;
    const int wid = tid >> 6, l = tid & 63;
    const int bkBase = blockIdx.x * 8;

    // staging identity: thread = (g=wid, lane=l); A-frag row c = l&15
    const int c_s = l & 15;
    const int bk_s = bkBase + wid;
    const int b_s = bk_s >> 11;
    const int idx_s = lidx[bk_s];
    const size_t base_s = (size_t)b_s * NN + idx_s;
    const int cand = cands[base_s * CC + c_s];
    const float* erow = emb + (size_t)cand * ED;
    const int kb = (l >> 4) * 8;
    const int ht = wid;

    f32x4 z = {0.f, 0.f, 0.f, 0.f};
    f32x4 acc[8][4];
#pragma unroll
    for (int g = 0; g < 8; ++g)
#pragma unroll
        for (int nc = 0; nc < 4; ++nc) acc[g][nc] = z;

    for (int ks = 0; ks < 10; ++ks) {
        int k = ks * 32 + kb;
        unsigned short v[8];
        if (k + 8 <= ED) {
            float4 x = *(const float4*)(erow + k);
            float4 y = *(const float4*)(erow + k + 4);
            v[0] = f2bf(x.x); v[1] = f2bf(x.y); v[2] = f2bf(x.z); v[3] = f2bf(x.w);
            v[4] = f2bf(y.x); v[5] = f2bf(y.y); v[6] = f2bf(y.z); v[7] = f2bf(y.w);
        } else {
#pragma unroll
            for (int j = 0; j < 8; ++j)
                v[j] = (k + j < ED) ? f2bf(erow[k + j]) : (unsigned short)0;
        }
        *(short8*)&As[tid * 8] = *(short8*)v;
        __syncthreads();

        short8 af[8];
#pragma unroll
        for (int g = 0; g < 8; ++g)
            af[g] = *(const short8*)&As[(g * 64 + l) * 8];
#pragma unroll
        for (int nc = 0; nc < 4; ++nc) {
            short8 bf = *(const short8*)&w1ef[(((size_t)(ht * 4 + nc) * 10 + ks) * 64 + l) * 8];
#pragma unroll
            for (int g = 0; g < 8; ++g)
                acc[g][nc] = MFMA16(af[g], bf, acc[g][nc]);
        }
        __syncthreads();
    }

    float w2v[4];
#pragma unroll
    for (int nc = 0; nc < 4; ++nc) w2v[nc] = W2[ht * 64 + nc * 16 + (l & 15)];

#pragma unroll
    for (int g = 0; g < 8; ++g) {
        const int bk = bkBase + g;
        float s0 = 0.f, s1 = 0.f, s2 = 0.f, s3 = 0.f;
#pragma unroll
        for (int nc = 0; nc < 4; ++nc) {
            int col = ht * 64 + nc * 16 + (l & 15);
            float sp = span_part[(size_t)bk * HD + col];
            f32x4 a = acc[g][nc];
            s0 += fmaxf(a[0] + sp, 0.f) * w2v[nc];
            s1 += fmaxf(a[1] + sp, 0.f) * w2v[nc];
            s2 += fmaxf(a[2] + sp, 0.f) * w2v[nc];
            s3 += fmaxf(a[3] + sp, 0.f) * w2v[nc];
        }
#pragma unroll
        for (int m = 1; m < 16; m <<= 1) {
            s0 += __shfl_xor(s0, m, 64);
            s1 += __shfl_xor(s1, m, 64);
            s2 += __shfl_xor(s2, m, 64);
            s3 += __shfl_xor(s3, m, 64);
        }
        if ((l & 15) == 0) {
            int r0 = (l >> 4) * 4;
            partials[((size_t)bk * 16 + r0 + 0) * 8 + ht] = s0;
            partials[((size_t)bk * 16 + r0 + 1) * 8 + ht] = s1;
            partials[((size_t)bk * 16 + r0 + 2) * 8 + ht] = s2;
            partials[((size_t)bk * 16 + r0 + 3) * 8 + ht] = s3;
        }
    }
}

// ---------------------------------------------------------------------------
// Masked BCE over 65536 (bk, c) items -> 64 block partials
// ---------------------------------------------------------------------------
__global__ __launch_bounds__(256) void bce_partial(
    const float* __restrict__ partials,
    const float* __restrict__ targets,
    const int* __restrict__ lidx,
    const int* __restrict__ clens,
    const float* __restrict__ b2,
    float* __restrict__ bp)
{
    const int tid = threadIdx.x;
    const int t0 = (blockIdx.x * 256 + tid) * 4;
    const float b2v = b2[0];
    float s = 0.f;
#pragma unroll
    for (int q = 0; q < 4; ++q) {
        int item = t0 + q;
        int bk = item >> 4, c = item & 15;
        int b = bk >> 11;
        int idx = lidx[bk];
        size_t base = (size_t)b * NN + idx;
        int len = clens[base];
        if (len > CC) len = CC;
        if (c < len) {
            const float* p = partials + (size_t)item * 8;
            float sc = ((p[0] + p[1]) + (p[2] + p[3])) +
                       ((p[4] + p[5]) + (p[6] + p[7])) + b2v;
            float tg = targets[base * CC + c];
            s += fmaxf(sc, 0.f) + log1pf(expf(-fabsf(sc))) - sc * tg;
        }
    }
    __shared__ float red[4];
#pragma unroll
    for (int m = 32; m; m >>= 1) s += __shfl_xor(s, m, 64);
    if ((tid & 63) == 0) red[tid >> 6] = s;
    __syncthreads();
    if (tid == 0) bp[blockIdx.x] = red[0] + red[1] + red[2] + red[3];
}

__global__ __launch_bounds__(64) void final_reduce(
    const float* __restrict__ bp, float* __restrict__ out)
{
    float s = bp[threadIdx.x];
#pragma unroll
    for (int m = 32; m; m >>= 1) s += __shfl_xor(s, m, 64);
    if (threadIdx.x == 0) out[0] = s;   // WEIGHT = 1.0
}

// ---------------------------------------------------------------------------
extern "C" void kernel_launch(void* const* d_in, const int* in_sizes, int n_in,
                              void* d_out, int out_size, void* d_ws, size_t ws_size,
                              hipStream_t stream) {
    const float* span    = (const float*)d_in[0];
    const float* targets = (const float*)d_in[1];
    const float* emb     = (const float*)d_in[2];
    const float* W1      = (const float*)d_in[3];
    const float* b1      = (const float*)d_in[4];
    const float* W2      = (const float*)d_in[5];
    const float* b2      = (const float*)d_in[6];
    const int*   lidx    = (const int*)d_in[7];
    const int*   cands   = (const int*)d_in[8];
    const int*   clens   = (const int*)d_in[9];

    char* ws = (char*)d_ws;
    unsigned short* W1sT      = (unsigned short*)(ws);             // 2 MB
    unsigned short* w1ef      = (unsigned short*)(ws + 2097152);   // 320 KB
    unsigned short* A16       = (unsigned short*)(ws + 2424832);   // 16 MB
    float*          span_part = (float*)(ws + 19202048);           // 8 MB
    float*          partials  = (float*)(ws + 27590656);           // 2 MB
    float*          bp        = (float*)(ws + 29687808);           // 256 B

    prep_weights<<<336, 256, 0, stream>>>(W1, W1sT, w1ef);
    gather_span<<<4096, 256, 0, stream>>>(span, lidx, A16);
    dim3 gD(HD / 64, 4096 / 128);
    span_gemm<<<gD, 256, 0, stream>>>(A16, W1sT, b1, span_part);
    ent_mfma<<<512, 512, 0, stream>>>(w1ef, span_part, emb, W2, lidx, cands, partials);
    bce_partial<<<64, 256, 0, stream>>>(partials, targets, lidx, clens, b2, bp);
    final_reduce<<<1, 64, 0, stream>>>(bp, (float*)d_out);
}

// Round 3
// 83.384 us; speedup vs baseline: 4.1798x; 1.1585x over previous
//
#include <hip/hip_runtime.h>
#include <math.h>

#define NN 4096
#define CC 16
#define DSP 2048
#define ED 300
#define HD 512

typedef __attribute__((ext_vector_type(8))) short short8;
typedef __attribute__((ext_vector_type(4))) float f32x4;

#define MFMA16(a, b, c) __builtin_amdgcn_mfma_f32_16x16x32_bf16((a), (b), (c), 0, 0, 0)

__device__ __forceinline__ unsigned short f2bf(float x) {
    unsigned u = __builtin_bit_cast(unsigned, x);
    u += 0x7FFFu + ((u >> 16) & 1u);   // RNE
    return (unsigned short)(u >> 16);
}

__device__ __forceinline__ void gl_lds16(const void* g, void* l) {
    __builtin_amdgcn_global_load_lds(
        (const __attribute__((address_space(1))) unsigned*)g,
        (__attribute__((address_space(3))) unsigned*)l, 16, 0, 0);
}

// ---------------------------------------------------------------------------
// Kernel 1 (merged): weight prep + span gather.
// bid <  256 : W1sT[n][k] = bf16(W1[k][n]) 64x64 LDS-transpose tiles
// bid <  336 : w1ef fragment-ready entity weights (zero-padded 300->320)
// bid >= 336 : gather selected span rows -> bf16 A16[bk][2048]
// ---------------------------------------------------------------------------
__global__ __launch_bounds__(256) void prep_and_gather(
    const float* __restrict__ W1,
    const float* __restrict__ span,
    const int*   __restrict__ lidx,
    unsigned short* __restrict__ W1sT,
    unsigned short* __restrict__ w1ef,
    unsigned short* __restrict__ A16)
{
    __shared__ float t[64][65];
    const int bid = blockIdx.x, tid = threadIdx.x;

    if (bid >= 336) {
        const int bk = bid - 336;
        const int b = bk >> 11;
        const float* src = span + ((size_t)b * NN + lidx[bk]) * DSP;
        float4 x = *(const float4*)(src + tid * 8);
        float4 y = *(const float4*)(src + tid * 8 + 4);
        unsigned short v[8] = { f2bf(x.x), f2bf(x.y), f2bf(x.z), f2bf(x.w),
                                f2bf(y.x), f2bf(y.y), f2bf(y.z), f2bf(y.w) };
        *(short8*)&A16[(size_t)bk * DSP + tid * 8] = *(short8*)v;
        return;
    }
    if (bid < 256) {
        const int k0 = (bid >> 3) * 64, n0 = (bid & 7) * 64;
#pragma unroll
        for (int p = 0; p < 16; ++p) {
            int flat = p * 256 + tid;
            int r = flat >> 6, c = flat & 63;
            t[r][c] = W1[(size_t)(k0 + r) * HD + n0 + c];
        }
        __syncthreads();
#pragma unroll
        for (int p = 0; p < 16; ++p) {
            int flat = p * 256 + tid;
            int c = flat >> 6, r = flat & 63;
            W1sT[(size_t)(n0 + c) * DSP + k0 + r] = f2bf(t[r][c]);
        }
    } else {
        int t0 = (bid - 256) * 256 + tid;   // 0..20479
        int lane = t0 & 63;
        int ks = (t0 >> 6) % 10;
        int ncg = (t0 >> 6) / 10;
        int col = ncg * 16 + (lane & 15);
        int kb = ks * 32 + ((lane >> 4) << 3);
        unsigned short v[8];
#pragma unroll
        for (int j = 0; j < 8; ++j) {
            int k = kb + j;
            v[j] = (k < ED) ? f2bf(W1[(size_t)(DSP + k) * HD + col]) : (unsigned short)0;
        }
        *(short8*)&w1ef[(size_t)t0 * 8] = *(short8*)v;
    }
}

// ---------------------------------------------------------------------------
// Kernel 2: span GEMM. C[4096][512] = A16 @ W1sT^T + b1.
// BM=BN=64, BK=64, dbuf LDS, min 2-phase (prefetch-before-compute, 1 barrier
// per step), XOR read-swizzle via pre-swizzled global source, XCD swizzle.
// ---------------------------------------------------------------------------
__global__ __launch_bounds__(256) void span_gemm(
    const unsigned short* __restrict__ A16,   // [4096][2048] bf16
    const unsigned short* __restrict__ BT,    // [512][2048]  bf16
    const float* __restrict__ b1,
    float* __restrict__ Cout)                 // [4096][512] f32 (+b1)
{
    __shared__ __align__(16) unsigned short As[2][64 * 64];
    __shared__ __align__(16) unsigned short Bs[2][64 * 64];
    const int tid = threadIdx.x;
    const int l = tid & 63, wid = tid >> 6;
    const int wr = (wid >> 1) * 32, wc = (wid & 1) * 32;

    // bijective XCD swizzle: XCD x gets row-blocks [x*8, x*8+8), all 8 cols
    const int bid = blockIdx.x;
    const int brow = ((bid & 7) * 8 + ((bid >> 3) >> 3)) * 64;
    const int bcol = (((bid >> 3) & 7)) * 64;

    // staging: slot s = row*8 + chunk; source chunk pre-swizzled (rule #21)
    const int s0 = tid, s1 = tid + 256;
    const int r0 = s0 >> 3, c0 = ((s0 & 7) ^ (r0 & 7)) * 8;
    const int r1 = s1 >> 3, c1 = ((s1 & 7) ^ (r1 & 7)) * 8;
    const unsigned short* ga0 = A16 + (size_t)(brow + r0) * DSP + c0;
    const unsigned short* ga1 = A16 + (size_t)(brow + r1) * DSP + c1;
    const unsigned short* gb0 = BT + (size_t)(bcol + r0) * DSP + c0;
    const unsigned short* gb1 = BT + (size_t)(bcol + r1) * DSP + c1;

    // fragment read offsets (shorts), swizzled chunk = q ^ (row&7)
    int offA[2][2], offB[2][2];
#pragma unroll
    for (int mf = 0; mf < 2; ++mf) {
        int row = wr + mf * 16 + (l & 15);
#pragma unroll
        for (int kk = 0; kk < 2; ++kk)
            offA[mf][kk] = row * 64 + (((kk * 4) + (l >> 4)) ^ (row & 7)) * 8;
    }
#pragma unroll
    for (int nf = 0; nf < 2; ++nf) {
        int row = wc + nf * 16 + (l & 15);
#pragma unroll
        for (int kk = 0; kk < 2; ++kk)
            offB[nf][kk] = row * 64 + (((kk * 4) + (l >> 4)) ^ (row & 7)) * 8;
    }

    f32x4 z = {0.f, 0.f, 0.f, 0.f};
    f32x4 acc[2][2] = {{z, z}, {z, z}};

    auto stage = [&](int buf, int k0) {
        gl_lds16(ga0 + k0, &As[buf][s0 * 8]);
        gl_lds16(ga1 + k0, &As[buf][s1 * 8]);
        gl_lds16(gb0 + k0, &Bs[buf][s0 * 8]);
        gl_lds16(gb1 + k0, &Bs[buf][s1 * 8]);
    };

    stage(0, 0);
    __syncthreads();          // compiler drains vmcnt(0) before s_barrier
    int cur = 0;
    for (int t = 0; t < 32; ++t) {
        if (t < 31) stage(cur ^ 1, (t + 1) * 64);   // in flight across MFMA
        short8 am[2][2], bn[2][2];
#pragma unroll
        for (int mf = 0; mf < 2; ++mf)
#pragma unroll
            for (int kk = 0; kk < 2; ++kk)
                am[mf][kk] = *(const short8*)&As[cur][offA[mf][kk]];
#pragma unroll
        for (int nf = 0; nf < 2; ++nf)
#pragma unroll
            for (int kk = 0; kk < 2; ++kk)
                bn[nf][kk] = *(const short8*)&Bs[cur][offB[nf][kk]];
#pragma unroll
        for (int m = 0; m < 2; ++m)
#pragma unroll
            for (int n = 0; n < 2; ++n)
#pragma unroll
                for (int kk = 0; kk < 2; ++kk)
                    acc[m][n] = MFMA16(am[m][kk], bn[n][kk], acc[m][n]);
        __syncthreads();      // drains vmcnt(0): next buffer ready
        cur ^= 1;
    }

#pragma unroll
    for (int n = 0; n < 2; ++n) {
        int col = bcol + wc + n * 16 + (l & 15);
        float b1v = b1[col];
#pragma unroll
        for (int m = 0; m < 2; ++m) {
            int row0 = brow + wr + m * 16 + (l >> 4) * 4;
#pragma unroll
            for (int r = 0; r < 4; ++r)
                Cout[(size_t)(row0 + r) * HD + col] = acc[m][n][r] + b1v;
        }
    }
}

// ---------------------------------------------------------------------------
// Kernel 3: entity MFMA + fused ReLU/W2/BCE epilogue.
// 8 waves x 8 bk pairs; dbuf reg-staged candidate rows (issue-early /
// write-late), 1 barrier per K-step; block emits ONE partial loss value.
// ---------------------------------------------------------------------------
__global__ __launch_bounds__(512) void ent_mfma(
    const unsigned short* __restrict__ w1ef,
    const float* __restrict__ span_part,  // [4096][512], includes b1
    const float* __restrict__ emb,        // [V][300] f32
    const float* __restrict__ W2,         // [512]
    const float* __restrict__ b2,         // [1]
    const int*   __restrict__ lidx,       // [B*K]
    const int*   __restrict__ cands,      // [B*N*16]
    const int*   __restrict__ clens,      // [B*N]
    const float* __restrict__ targets,    // [B*N*16]
    float* __restrict__ blockPartial)     // [512]
{
    __shared__ __align__(16) unsigned short As[2][8 * 64 * 8];  // 16 KB
    __shared__ float shp[8][16][8];                             // 4 KB
    __shared__ float wred[8];
    const int tid = threadIdx.x;
    const int wid = tid >> 6, l = tid & 63;
    const int bkBase = blockIdx.x * 8;

    // staging identity: candidate c = l&15, k-chunk = (l>>4)*8, bk = wid
    const int bk_s = bkBase + wid;
    const size_t base_s = (size_t)(bk_s >> 11) * NN + lidx[bk_s];
    const float* erow = emb + (size_t)cands[base_s * CC + (l & 15)] * ED;
    const int kb = (l >> 4) * 8;
    const int ht = wid;

    // prologue: ks=0 (k = kb < 32, always in range)
    float4 lx = *(const float4*)(erow + kb);
    float4 ly = *(const float4*)(erow + kb + 4);
    {
        unsigned short v[8] = { f2bf(lx.x), f2bf(lx.y), f2bf(lx.z), f2bf(lx.w),
                                f2bf(ly.x), f2bf(ly.y), f2bf(ly.z), f2bf(ly.w) };
        *(short8*)&As[0][tid * 8] = *(short8*)v;
    }
    __syncthreads();

    f32x4 z = {0.f, 0.f, 0.f, 0.f};
    f32x4 acc[8][4];
#pragma unroll
    for (int g = 0; g < 8; ++g)
#pragma unroll
        for (int nc = 0; nc < 4; ++nc) acc[g][nc] = z;

    int cur = 0;
    for (int ks = 0; ks < 10; ++ks) {
        const bool pf = (ks < 9);
        // T14 issue-early: next step's loads fly under this step's MFMAs
        if (pf) {
            int k = (ks + 1) * 32 + kb;
            if (k + 8 <= ED) {
                lx = *(const float4*)(erow + k);
                ly = *(const float4*)(erow + k + 4);
            } else {
                float tmp[8];
#pragma unroll
                for (int j = 0; j < 8; ++j) tmp[j] = (k + j < ED) ? erow[k + j] : 0.f;
                lx = make_float4(tmp[0], tmp[1], tmp[2], tmp[3]);
                ly = make_float4(tmp[4], tmp[5], tmp[6], tmp[7]);
            }
        }
        short8 af[8];
#pragma unroll
        for (int g = 0; g < 8; ++g)
            af[g] = *(const short8*)&As[cur][(g * 64 + l) * 8];
#pragma unroll
        for (int nc = 0; nc < 4; ++nc) {
            short8 bf = *(const short8*)&w1ef[(((size_t)(ht * 4 + nc) * 10 + ks) * 64 + l) * 8];
#pragma unroll
            for (int g = 0; g < 8; ++g)
                acc[g][nc] = MFMA16(af[g], bf, acc[g][nc]);
        }
        if (pf) {  // write-late into the other buffer
            unsigned short v[8] = { f2bf(lx.x), f2bf(lx.y), f2bf(lx.z), f2bf(lx.w),
                                    f2bf(ly.x), f2bf(ly.y), f2bf(ly.z), f2bf(ly.w) };
            *(short8*)&As[cur ^ 1][tid * 8] = *(short8*)v;
        }
        __syncthreads();
        cur ^= 1;
    }

    // epilogue: relu(acc + span_h) . W2, 16-lane reduce -> shp[g][c][ht]
    float w2v[4];
#pragma unroll
    for (int nc = 0; nc < 4; ++nc) w2v[nc] = W2[ht * 64 + nc * 16 + (l & 15)];

#pragma unroll
    for (int g = 0; g < 8; ++g) {
        const int bk = bkBase + g;
        float s0 = 0.f, s1 = 0.f, s2 = 0.f, s3 = 0.f;
#pragma unroll
        for (int nc = 0; nc < 4; ++nc) {
            float sp = span_part[(size_t)bk * HD + ht * 64 + nc * 16 + (l & 15)];
            f32x4 a = acc[g][nc];
            s0 += fmaxf(a[0] + sp, 0.f) * w2v[nc];
            s1 += fmaxf(a[1] + sp, 0.f) * w2v[nc];
            s2 += fmaxf(a[2] + sp, 0.f) * w2v[nc];
            s3 += fmaxf(a[3] + sp, 0.f) * w2v[nc];
        }
#pragma unroll
        for (int m = 1; m < 16; m <<= 1) {
            s0 += __shfl_xor(s0, m, 64);
            s1 += __shfl_xor(s1, m, 64);
            s2 += __shfl_xor(s2, m, 64);
            s3 += __shfl_xor(s3, m, 64);
        }
        if ((l & 15) == 0) {
            int r0 = (l >> 4) * 4;
            shp[g][r0 + 0][ht] = s0;
            shp[g][r0 + 1][ht] = s1;
            shp[g][r0 + 2][ht] = s2;
            shp[g][r0 + 3][ht] = s3;
        }
    }
    __syncthreads();

    // fused masked BCE: 128 threads own one (g, c) each
    float val = 0.f;
    if (tid < 128) {
        const int g = tid >> 4, c = tid & 15;
        const int bk = bkBase + g;
        const size_t base = (size_t)(bk >> 11) * NN + lidx[bk];
        int len = clens[base];
        if (len > CC) len = CC;
        if (c < len) {
            const float* p = &shp[g][c][0];
            float sc = ((p[0] + p[1]) + (p[2] + p[3])) +
                       ((p[4] + p[5]) + (p[6] + p[7])) + b2[0];
            float tg = targets[base * CC + c];
            val = fmaxf(sc, 0.f) + log1pf(expf(-fabsf(sc))) - sc * tg;
        }
    }
#pragma unroll
    for (int m = 32; m; m >>= 1) val += __shfl_xor(val, m, 64);
    if (l == 0) wred[wid] = val;
    __syncthreads();
    if (tid == 0) {
        float s = 0.f;
#pragma unroll
        for (int w = 0; w < 8; ++w) s += wred[w];
        blockPartial[blockIdx.x] = s;
    }
}

// ---------------------------------------------------------------------------
// Kernel 4: final deterministic reduce of 512 block partials
// ---------------------------------------------------------------------------
__global__ __launch_bounds__(256) void final_reduce(
    const float* __restrict__ bp, float* __restrict__ out)
{
    __shared__ float red[4];
    float s = bp[threadIdx.x] + bp[threadIdx.x + 256];
#pragma unroll
    for (int m = 32; m; m >>= 1) s += __shfl_xor(s, m, 64);
    if ((threadIdx.x & 63) == 0) red[threadIdx.x >> 6] = s;
    __syncthreads();
    if (threadIdx.x == 0)
        out[0] = (red[0] + red[1]) + (red[2] + red[3]);   // WEIGHT = 1.0
}

// ---------------------------------------------------------------------------
extern "C" void kernel_launch(void* const* d_in, const int* in_sizes, int n_in,
                              void* d_out, int out_size, void* d_ws, size_t ws_size,
                              hipStream_t stream) {
    const float* span    = (const float*)d_in[0];
    const float* targets = (const float*)d_in[1];
    const float* emb     = (const float*)d_in[2];
    const float* W1      = (const float*)d_in[3];
    const float* b1      = (const float*)d_in[4];
    const float* W2      = (const float*)d_in[5];
    const float* b2      = (const float*)d_in[6];
    const int*   lidx    = (const int*)d_in[7];
    const int*   cands   = (const int*)d_in[8];
    const int*   clens   = (const int*)d_in[9];

    char* ws = (char*)d_ws;
    unsigned short* W1sT      = (unsigned short*)(ws);             // 2 MB
    unsigned short* w1ef      = (unsigned short*)(ws + 2097152);   // 320 KB
    unsigned short* A16       = (unsigned short*)(ws + 2424832);   // 16 MB
    float*          span_part = (float*)(ws + 19202048);           // 8 MB
    float*          bpart     = (float*)(ws + 27590656);           // 2 KB

    prep_and_gather<<<4432, 256, 0, stream>>>(W1, span, lidx, W1sT, w1ef, A16);
    span_gemm<<<512, 256, 0, stream>>>(A16, W1sT, b1, span_part);
    ent_mfma<<<512, 512, 0, stream>>>(w1ef, span_part, emb, W2, b2,
                                      lidx, cands, clens, targets, bpart);
    final_reduce<<<1, 256, 0, stream>>>(bpart, (float*)d_out);
}

// Round 4
// 66.690 us; speedup vs baseline: 5.2260x; 1.2503x over previous
//
#include <hip/hip_runtime.h>
#include <math.h>

#define NN 4096
#define CC 16
#define DSP 2048
#define ED 300
#define HD 512

typedef __attribute__((ext_vector_type(8))) short short8;
typedef __attribute__((ext_vector_type(4))) float f32x4;

#define MFMA16(a, b, c) __builtin_amdgcn_mfma_f32_16x16x32_bf16((a), (b), (c), 0, 0, 0)

__device__ __forceinline__ unsigned short f2bf(float x) {
    unsigned u = __builtin_bit_cast(unsigned, x);
    u += 0x7FFFu + ((u >> 16) & 1u);   // RNE
    return (unsigned short)(u >> 16);
}

__device__ __forceinline__ void gl_lds16(const void* g, void* l) {
    __builtin_amdgcn_global_load_lds(
        (const __attribute__((address_space(1))) unsigned*)g,
        (__attribute__((address_space(3))) unsigned*)l, 16, 0, 0);
}

// ---------------------------------------------------------------------------
// Kernel 1: weight prep + span gather + length prefix-scan (1 block).
// bid <  256 : W1sT[n][k] = bf16(W1[k][n]) 64x64 LDS-transpose tiles
// bid <  336 : w1ef fragment-ready entity weights (zero-padded 300->320)
// bid <  4432: gather selected span rows -> bf16 A16[bk][2048]
// bid == 4432: exclusive prefix scan of per-bk candidate counts -> off[4097]
// ---------------------------------------------------------------------------
__global__ __launch_bounds__(256) void prep_gather_scan(
    const float* __restrict__ W1,
    const float* __restrict__ span,
    const int*   __restrict__ lidx,
    const int*   __restrict__ clens,
    unsigned short* __restrict__ W1sT,
    unsigned short* __restrict__ w1ef,
    unsigned short* __restrict__ A16,
    int*            __restrict__ off)      // [4097], off[4096] = total
{
    const int bid = blockIdx.x, tid = threadIdx.x;

    if (bid == 4432) {   // scan block
        __shared__ int ls[256];
        int myl[16];
        int msum = 0;
#pragma unroll
        for (int j = 0; j < 16; ++j) {
            int bk = tid * 16 + j;
            size_t base = (size_t)(bk >> 11) * NN + lidx[bk];
            int len = clens[base];
            len = len < 0 ? 0 : (len > CC ? CC : len);
            myl[j] = len; msum += len;
        }
        ls[tid] = msum;
        __syncthreads();
        for (int d = 1; d < 256; d <<= 1) {
            int v = (tid >= d) ? ls[tid - d] : 0;
            __syncthreads();
            ls[tid] += v;
            __syncthreads();
        }
        int run = ls[tid] - msum;   // exclusive prefix
#pragma unroll
        for (int j = 0; j < 16; ++j) { off[tid * 16 + j] = run; run += myl[j]; }
        if (tid == 255) off[4096] = run;
        return;
    }
    if (bid >= 336) {    // span gather
        const int bk = bid - 336;
        const float* src = span + ((size_t)(bk >> 11) * NN + lidx[bk]) * DSP;
        float4 x = *(const float4*)(src + tid * 8);
        float4 y = *(const float4*)(src + tid * 8 + 4);
        unsigned short v[8] = { f2bf(x.x), f2bf(x.y), f2bf(x.z), f2bf(x.w),
                                f2bf(y.x), f2bf(y.y), f2bf(y.z), f2bf(y.w) };
        *(short8*)&A16[(size_t)bk * DSP + tid * 8] = *(short8*)v;
        return;
    }
    if (bid < 256) {     // W1 span-part transpose
        __shared__ float t[64][65];
        const int k0 = (bid >> 3) * 64, n0 = (bid & 7) * 64;
#pragma unroll
        for (int p = 0; p < 16; ++p) {
            int flat = p * 256 + tid;
            int r = flat >> 6, c = flat & 63;
            t[r][c] = W1[(size_t)(k0 + r) * HD + n0 + c];
        }
        __syncthreads();
#pragma unroll
        for (int p = 0; p < 16; ++p) {
            int flat = p * 256 + tid;
            int c = flat >> 6, r = flat & 63;
            W1sT[(size_t)(n0 + c) * DSP + k0 + r] = f2bf(t[r][c]);
        }
    } else {             // entity-weight fragments
        int t0 = (bid - 256) * 256 + tid;   // 0..20479
        int lane = t0 & 63;
        int ks = (t0 >> 6) % 10;
        int ncg = (t0 >> 6) / 10;
        int col = ncg * 16 + (lane & 15);
        int kb = ks * 32 + ((lane >> 4) << 3);
        unsigned short v[8];
#pragma unroll
        for (int j = 0; j < 8; ++j) {
            int k = kb + j;
            v[j] = (k < ED) ? f2bf(W1[(size_t)(DSP + k) * HD + col]) : (unsigned short)0;
        }
        *(short8*)&w1ef[(size_t)t0 * 8] = *(short8*)v;
    }
}

// ---------------------------------------------------------------------------
// Kernel 2: span GEMM (bid < 512) + compaction fill (bid >= 512).
// GEMM: BM=BN=64, BK=64, dbuf LDS, 1 barrier/step, XOR read-swizzle via
// pre-swizzled global source, bijective XCD swizzle.
// Fill: pack valid (bk,c) slots -> compact_cand / compact_meta.
// ---------------------------------------------------------------------------
__global__ __launch_bounds__(256) void gemm_and_fill(
    const unsigned short* __restrict__ A16,   // [4096][2048] bf16
    const unsigned short* __restrict__ BT,    // [512][2048]  bf16
    const float* __restrict__ b1,
    float* __restrict__ Cout,                 // [4096][512] f32 (+b1)
    const int* __restrict__ lidx,
    const int* __restrict__ cands,
    const int* __restrict__ clens,
    const int* __restrict__ off,
    int* __restrict__ compact_cand,
    int* __restrict__ compact_meta)
{
    const int tid = threadIdx.x;

    if (blockIdx.x >= 512) {     // ---- fill path ----
        int fb = blockIdx.x - 512;
        int item0 = (fb * 256 + tid) * 4;
#pragma unroll
        for (int q = 0; q < 4; ++q) {
            int item = item0 + q;
            int bk = item >> 4, c = item & 15;
            size_t base = (size_t)(bk >> 11) * NN + lidx[bk];
            int len = clens[base];
            len = len > CC ? CC : len;
            if (c < len) {
                int pos = off[bk] + c;
                compact_cand[pos] = cands[base * CC + c];
                compact_meta[pos] = item;   // (bk<<4)|c
            }
        }
        return;
    }

    // ---- GEMM path ----
    __shared__ __align__(16) unsigned short As[2][64 * 64];
    __shared__ __align__(16) unsigned short Bs[2][64 * 64];
    const int l = tid & 63, wid = tid >> 6;
    const int wr = (wid >> 1) * 32, wc = (wid & 1) * 32;

    const int bid = blockIdx.x;
    const int brow = ((bid & 7) * 8 + ((bid >> 3) >> 3)) * 64;
    const int bcol = (((bid >> 3) & 7)) * 64;

    const int s0 = tid, s1 = tid + 256;
    const int r0 = s0 >> 3, c0 = ((s0 & 7) ^ (r0 & 7)) * 8;
    const int r1 = s1 >> 3, c1 = ((s1 & 7) ^ (r1 & 7)) * 8;
    const unsigned short* ga0 = A16 + (size_t)(brow + r0) * DSP + c0;
    const unsigned short* ga1 = A16 + (size_t)(brow + r1) * DSP + c1;
    const unsigned short* gb0 = BT + (size_t)(bcol + r0) * DSP + c0;
    const unsigned short* gb1 = BT + (size_t)(bcol + r1) * DSP + c1;

    int offA[2][2], offB[2][2];
#pragma unroll
    for (int mf = 0; mf < 2; ++mf) {
        int row = wr + mf * 16 + (l & 15);
#pragma unroll
        for (int kk = 0; kk < 2; ++kk)
            offA[mf][kk] = row * 64 + (((kk * 4) + (l >> 4)) ^ (row & 7)) * 8;
    }
#pragma unroll
    for (int nf = 0; nf < 2; ++nf) {
        int row = wc + nf * 16 + (l & 15);
#pragma unroll
        for (int kk = 0; kk < 2; ++kk)
            offB[nf][kk] = row * 64 + (((kk * 4) + (l >> 4)) ^ (row & 7)) * 8;
    }

    f32x4 z = {0.f, 0.f, 0.f, 0.f};
    f32x4 acc[2][2] = {{z, z}, {z, z}};

    auto stage = [&](int buf, int k0) {
        gl_lds16(ga0 + k0, &As[buf][s0 * 8]);
        gl_lds16(ga1 + k0, &As[buf][s1 * 8]);
        gl_lds16(gb0 + k0, &Bs[buf][s0 * 8]);
        gl_lds16(gb1 + k0, &Bs[buf][s1 * 8]);
    };

    stage(0, 0);
    __syncthreads();
    int cur = 0;
    for (int t = 0; t < 32; ++t) {
        if (t < 31) stage(cur ^ 1, (t + 1) * 64);
        short8 am[2][2], bn[2][2];
#pragma unroll
        for (int mf = 0; mf < 2; ++mf)
#pragma unroll
            for (int kk = 0; kk < 2; ++kk)
                am[mf][kk] = *(const short8*)&As[cur][offA[mf][kk]];
#pragma unroll
        for (int nf = 0; nf < 2; ++nf)
#pragma unroll
            for (int kk = 0; kk < 2; ++kk)
                bn[nf][kk] = *(const short8*)&Bs[cur][offB[nf][kk]];
#pragma unroll
        for (int m = 0; m < 2; ++m)
#pragma unroll
            for (int n = 0; n < 2; ++n)
#pragma unroll
                for (int kk = 0; kk < 2; ++kk)
                    acc[m][n] = MFMA16(am[m][kk], bn[n][kk], acc[m][n]);
        __syncthreads();
        cur ^= 1;
    }

#pragma unroll
    for (int n = 0; n < 2; ++n) {
        int col = bcol + wc + n * 16 + (l & 15);
        float b1v = b1[col];
#pragma unroll
        for (int m = 0; m < 2; ++m) {
            int row0 = brow + wr + m * 16 + (l >> 4) * 4;
#pragma unroll
            for (int r = 0; r < 4; ++r)
                Cout[(size_t)(row0 + r) * HD + col] = acc[m][n][r] + b1v;
        }
    }
}

// ---------------------------------------------------------------------------
// Kernel 3: compacted entity MFMA + fused ReLU/W2/BCE epilogue.
// Block = 8 waves; wave w stages tile (bid*8+w) of 16 valid slots and owns
// h-col slice [w*64, w*64+64). Dbuf reg-staged emb rows, 1 barrier/K-step.
// Blocks past the dynamic slot count exit early with a zero partial.
// ---------------------------------------------------------------------------
__global__ __launch_bounds__(512) void ent_mfma(
    const unsigned short* __restrict__ w1ef,
    const float* __restrict__ span_part,  // [4096][512], includes b1
    const float* __restrict__ emb,        // [V][300] f32
    const float* __restrict__ W2,         // [512]
    const float* __restrict__ b2,         // [1]
    const int*   __restrict__ lidx,       // [B*K]
    const float* __restrict__ targets,    // [B*N*16]
    const int*   __restrict__ compact_cand,
    const int*   __restrict__ compact_meta,
    const int*   __restrict__ off,        // off[4096] = total
    float* __restrict__ blockPartial)     // [512]
{
    const int total = off[4096];
    const int bid = blockIdx.x;
    const int slotBase = bid * 128;
    const int tid = threadIdx.x;
    if (slotBase >= total) {
        if (tid == 0) blockPartial[bid] = 0.f;
        return;
    }

    __shared__ __align__(16) unsigned short As[2][8 * 64 * 8];  // 16 KB
    __shared__ float shp[8][16][8];                             // 4 KB
    __shared__ int   meta_s[128];
    __shared__ float wred[8];
    const int wid = tid >> 6, l = tid & 63;

    if (tid < 128) {
        int slot = slotBase + tid;
        meta_s[tid] = (slot < total) ? compact_meta[slot] : -1;
    }

    // staging identity: slot-in-tile = l&15, k-chunk = (l>>4)*8, tile = wid
    const int slot_s = slotBase + wid * 16 + (l & 15);
    const int cid = (slot_s < total) ? compact_cand[slot_s] : 0;
    const float* erow = emb + (size_t)cid * ED;
    const int kb = (l >> 4) * 8;
    const int ht = wid;

    // prologue: ks=0
    float4 lx = *(const float4*)(erow + kb);
    float4 ly = *(const float4*)(erow + kb + 4);
    {
        unsigned short v[8] = { f2bf(lx.x), f2bf(lx.y), f2bf(lx.z), f2bf(lx.w),
                                f2bf(ly.x), f2bf(ly.y), f2bf(ly.z), f2bf(ly.w) };
        *(short8*)&As[0][tid * 8] = *(short8*)v;
    }
    __syncthreads();

    f32x4 z = {0.f, 0.f, 0.f, 0.f};
    f32x4 acc[8][4];
#pragma unroll
    for (int g = 0; g < 8; ++g)
#pragma unroll
        for (int nc = 0; nc < 4; ++nc) acc[g][nc] = z;

    int cur = 0;
    for (int ks = 0; ks < 10; ++ks) {
        const bool pf = (ks < 9);
        if (pf) {   // T14 issue-early
            int k = (ks + 1) * 32 + kb;
            if (k + 8 <= ED) {
                lx = *(const float4*)(erow + k);
                ly = *(const float4*)(erow + k + 4);
            } else {
                float tmp[8];
#pragma unroll
                for (int j = 0; j < 8; ++j) tmp[j] = (k + j < ED) ? erow[k + j] : 0.f;
                lx = make_float4(tmp[0], tmp[1], tmp[2], tmp[3]);
                ly = make_float4(tmp[4], tmp[5], tmp[6], tmp[7]);
            }
        }
        short8 af[8];
#pragma unroll
        for (int g = 0; g < 8; ++g)
            af[g] = *(const short8*)&As[cur][(g * 64 + l) * 8];
#pragma unroll
        for (int nc = 0; nc < 4; ++nc) {
            short8 bf = *(const short8*)&w1ef[(((size_t)(ht * 4 + nc) * 10 + ks) * 64 + l) * 8];
#pragma unroll
            for (int g = 0; g < 8; ++g)
                acc[g][nc] = MFMA16(af[g], bf, acc[g][nc]);
        }
        if (pf) {   // write-late
            unsigned short v[8] = { f2bf(lx.x), f2bf(lx.y), f2bf(lx.z), f2bf(lx.w),
                                    f2bf(ly.x), f2bf(ly.y), f2bf(ly.z), f2bf(ly.w) };
            *(short8*)&As[cur ^ 1][tid * 8] = *(short8*)v;
        }
        __syncthreads();
        cur ^= 1;
    }

    // epilogue: relu(acc + span_h[bk(slot)]) . W2, 16-lane reduce
    float w2v[4];
#pragma unroll
    for (int nc = 0; nc < 4; ++nc) w2v[nc] = W2[ht * 64 + nc * 16 + (l & 15)];
    const int rq = (l >> 4) * 4;

#pragma unroll
    for (int g = 0; g < 8; ++g) {
        int bkR[4];
#pragma unroll
        for (int i = 0; i < 4; ++i) {
            int m = meta_s[g * 16 + rq + i];
            bkR[i] = (m >= 0) ? (m >> 4) : 0;
        }
        float s[4] = {0.f, 0.f, 0.f, 0.f};
#pragma unroll
        for (int nc = 0; nc < 4; ++nc) {
            int col = ht * 64 + nc * 16 + (l & 15);
            f32x4 a = acc[g][nc];
#pragma unroll
            for (int i = 0; i < 4; ++i) {
                float sp = span_part[(size_t)bkR[i] * HD + col];
                s[i] += fmaxf(a[i] + sp, 0.f) * w2v[nc];
            }
        }
#pragma unroll
        for (int m = 1; m < 16; m <<= 1) {
#pragma unroll
            for (int i = 0; i < 4; ++i) s[i] += __shfl_xor(s[i], m, 64);
        }
        if ((l & 15) == 0) {
#pragma unroll
            for (int i = 0; i < 4; ++i) shp[g][rq + i][ht] = s[i];
        }
    }
    __syncthreads();

    // fused BCE: 128 threads own one compacted slot each (all valid by const.)
    float val = 0.f;
    if (tid < 128) {
        int m = meta_s[tid];
        if (m >= 0) {
            int bk = m >> 4, c = m & 15;
            size_t base = (size_t)(bk >> 11) * NN + lidx[bk];
            const float* p = &shp[tid >> 4][tid & 15][0];
            float sc = ((p[0] + p[1]) + (p[2] + p[3])) +
                       ((p[4] + p[5]) + (p[6] + p[7])) + b2[0];
            float tg = targets[base * CC + c];
            val = fmaxf(sc, 0.f) + log1pf(expf(-fabsf(sc))) - sc * tg;
        }
    }
#pragma unroll
    for (int m = 32; m; m >>= 1) val += __shfl_xor(val, m, 64);
    if (l == 0) wred[wid] = val;
    __syncthreads();
    if (tid == 0) {
        float s = 0.f;
#pragma unroll
        for (int w = 0; w < 8; ++w) s += wred[w];
        blockPartial[bid] = s;
    }
}

// ---------------------------------------------------------------------------
// Kernel 4: final deterministic reduce of 512 block partials
// ---------------------------------------------------------------------------
__global__ __launch_bounds__(256) void final_reduce(
    const float* __restrict__ bp, float* __restrict__ out)
{
    __shared__ float red[4];
    float s = bp[threadIdx.x] + bp[threadIdx.x + 256];
#pragma unroll
    for (int m = 32; m; m >>= 1) s += __shfl_xor(s, m, 64);
    if ((threadIdx.x & 63) == 0) red[threadIdx.x >> 6] = s;
    __syncthreads();
    if (threadIdx.x == 0)
        out[0] = (red[0] + red[1]) + (red[2] + red[3]);   // WEIGHT = 1.0
}

// ---------------------------------------------------------------------------
extern "C" void kernel_launch(void* const* d_in, const int* in_sizes, int n_in,
                              void* d_out, int out_size, void* d_ws, size_t ws_size,
                              hipStream_t stream) {
    const float* span    = (const float*)d_in[0];
    const float* targets = (const float*)d_in[1];
    const float* emb     = (const float*)d_in[2];
    const float* W1      = (const float*)d_in[3];
    const float* b1      = (const float*)d_in[4];
    const float* W2      = (const float*)d_in[5];
    const float* b2      = (const float*)d_in[6];
    const int*   lidx    = (const int*)d_in[7];
    const int*   cands   = (const int*)d_in[8];
    const int*   clens   = (const int*)d_in[9];

    char* ws = (char*)d_ws;
    unsigned short* W1sT      = (unsigned short*)(ws);             // 2 MB
    unsigned short* w1ef      = (unsigned short*)(ws + 2097152);   // 320 KB
    unsigned short* A16       = (unsigned short*)(ws + 2424832);   // 16 MB
    float*          span_part = (float*)(ws + 19202048);           // 8 MB
    int*            off       = (int*)(ws + 27590656);             // 16.4 KB
    int*            ccand     = (int*)(ws + 27623424);             // 256 KB
    int*            cmeta     = (int*)(ws + 27885568);             // 256 KB
    float*          bpart     = (float*)(ws + 28147712);           // 2 KB

    prep_gather_scan<<<4433, 256, 0, stream>>>(W1, span, lidx, clens,
                                               W1sT, w1ef, A16, off);
    gemm_and_fill<<<576, 256, 0, stream>>>(A16, W1sT, b1, span_part,
                                           lidx, cands, clens, off, ccand, cmeta);
    ent_mfma<<<512, 512, 0, stream>>>(w1ef, span_part, emb, W2, b2,
                                      lidx, targets, ccand, cmeta, off, bpart);
    final_reduce<<<1, 256, 0, stream>>>(bpart, (float*)d_out);
}